// Round 8
// baseline (275.841 us; speedup 1.0000x reference)
//
#include <hip/hip_runtime.h>
#include <hip/hip_bf16.h>
#include <stdint.h>

#define DD 120
#define HD 15
#define LN_EPS 1e-5f

typedef __attribute__((ext_vector_type(8))) short bf16x8;
typedef __attribute__((ext_vector_type(4))) float f32x4;

__device__ __forceinline__ unsigned short f2bf(float f) {
    return __bfloat16_as_ushort(__float2bfloat16(f));
}

// ---- prep: pack weights as MFMA A-fragments with bias folded into k=120 ----
// W1bp: [24 t][4 kk][64 lane][8 e]; A-row n = padded qkv channel t*16+(lane&15)
//       tile t = part*8 + h (pos = part*128 + h*16 + i)
//       k<120: weight; k==120: bias (i<15) / 1.0 marker for V-head0-pad (part==2,h==0,i==15)
// W2bp: [8 t][4 kk][64 lane][8 e]; A-row n = out channel; k = head-padded o-channel;
//       kpad==15 carries out_b (fed by O[15]==1.0)
__global__ void prep_weights(const float* __restrict__ w1, const float* __restrict__ w2,
                             const float* __restrict__ b1, const float* __restrict__ b2,
                             unsigned short* __restrict__ W1bp, unsigned short* __restrict__ W2bp) {
    int idx = blockIdx.x * blockDim.x + threadIdx.x;
    int stride = gridDim.x * blockDim.x;
    for (int p = idx; p < 24 * 4 * 64 * 8; p += stride) {
        int e = p & 7, lane = (p >> 3) & 63, kk = (p >> 9) & 3, t = p >> 11;
        int pos = t * 16 + (lane & 15);
        int part = pos >> 7, rem = pos & 127, h = rem >> 4, i = rem & 15;
        int k = kk * 32 + (lane >> 4) * 8 + e;
        float v = 0.f;
        if (k < DD)        { if (i < HD) v = w1[(part * DD + h * HD + i) * DD + k]; }
        else if (k == DD)  { if (i < HD) v = b1[part * DD + h * HD + i];
                             else if (part == 2 && h == 0) v = 1.0f; }
        W1bp[p] = f2bf(v);
    }
    for (int p = idx; p < 8 * 4 * 64 * 8; p += stride) {
        int e = p & 7, lane = (p >> 3) & 63, kk = (p >> 9) & 3, t = p >> 11;
        int n = t * 16 + (lane & 15);
        int kpad = kk * 32 + (lane >> 4) * 8 + e;
        int i = kpad & 15;
        int h = kpad >> 4;
        float v = 0.f;
        if (n < DD) {
            if (i < HD) v = w2[n * DD + h * HD + i];
            else if (kpad == 15) v = b2[n];
        }
        W2bp[p] = f2bf(v);
    }
}

// ---- fused, persistent multi-tile: each WG strides over tiles of 64 tokens ----
// LDS 48KB -> 3 WG/CU; staging of tile t+1 double-buffered + overlapped with tile t.
__global__ __launch_bounds__(256, 3) void fused_attn(
    const float* __restrict__ voxel, const float* __restrict__ cnnf,
    const float* __restrict__ gamma, const float* __restrict__ beta,
    const unsigned short* __restrict__ W1bp, const unsigned short* __restrict__ W2bp,
    float* __restrict__ out, int ntile)
{
    // layout: [xs0 16K][obuf 16K][xs1 16K]
    // iter parity 0: cur=xs0, yf = xs0+obuf (smem+0)     (contiguous 32K)
    // iter parity 1: cur=xs1, yf = obuf+xs1 (smem+16384) (contiguous 32K)
    __shared__ __align__(16) char smem[49152];
    unsigned short* xs0  = (unsigned short*)smem;
    unsigned short* obuf = (unsigned short*)(smem + 16384);
    unsigned short* xs1  = (unsigned short*)(smem + 32768);

    const int tid = threadIdx.x;
    const int wave = tid >> 6, lane = tid & 63;
    const int lrow = lane & 15, lk = lane >> 4;
    const int w = wave;
    const int r7 = lrow & 7;
    const float scale = 0.25819888974716112567f;   // 1/sqrt(15)

    // persistent W2 A-frags (tiles w, w+4)
    bf16x8 A2[2][4];
    #pragma unroll
    for (int ti = 0; ti < 2; ++ti)
        #pragma unroll
        for (int kk = 0; kk < 4; ++kk)
            A2[ti][kk] = *(const bf16x8*)(W2bp + ((size_t)(((w + 4 * ti) * 4 + kk) * 64 + lane)) * 8);

    // W1 streaming buffers: A[0]=tile(u=0)=w, A[1]=tile(u=1)=8+w
    bf16x8 A[2][4];
    #pragma unroll
    for (int kk = 0; kk < 4; ++kk) {
        A[0][kk] = *(const bf16x8*)(W1bp + ((size_t)(((w) * 4 + kk) * 64 + lane)) * 8);
        A[1][kk] = *(const bf16x8*)(W1bp + ((size_t)(((8 + w) * 4 + kk) * 64 + lane)) * 8);
    }

    float4 f[8];
    int tile = blockIdx.x;

    // ---- staging load/write helpers (all compile-time indices) ----
    auto sload_lo = [&](int t) {   // f[0..3]
        #pragma unroll
        for (int jj = 0; jj < 4; ++jj) {
            int i = tid + jj * 256;
            int r = i / 30, c4 = i % 30;
            int gtok = t * 64 + r;
            const float* src = ((gtok & 1) ? cnnf : voxel) + (size_t)(gtok >> 1) * DD + c4 * 4;
            f[jj] = *(const float4*)src;
        }
    };
    auto sload_hi = [&](int t) {   // f[4..7], tail-guarded
        #pragma unroll
        for (int jj = 4; jj < 8; ++jj) {
            int i = tid + jj * 256;
            if (i < 1920) {
                int r = i / 30, c4 = i % 30;
                int gtok = t * 64 + r;
                const float* src = ((gtok & 1) ? cnnf : voxel) + (size_t)(gtok >> 1) * DD + c4 * 4;
                f[jj] = *(const float4*)src;
            }
        }
    };
    auto swrite = [&](unsigned short* xs) {
        #pragma unroll
        for (int jj = 0; jj < 8; ++jj) {
            int i = tid + jj * 256;
            if (jj < 4 || i < 1920) {
                int r = i / 30, c4 = i % 30;
                ushort4 hv;
                hv.x = f2bf(f[jj].x); hv.y = f2bf(f[jj].y);
                hv.z = f2bf(f[jj].z); hv.w = f2bf(f[jj].w);
                int c8 = c4 >> 1, sub = (c4 & 1) * 8;
                *(ushort4*)((char*)xs + r * 256 + ((c8 ^ (r & 7)) << 4) + sub) = hv;
            }
        }
        if (tid < 64) {   // pad chunk 15: x[120]=1.0 (bias), 121..127=0 (rewritten every tile)
            int r = tid;
            ushort4 p0; p0.x = 0x3F80; p0.y = 0; p0.z = 0; p0.w = 0;
            ushort4 z0; z0.x = 0; z0.y = 0; z0.z = 0; z0.w = 0;
            char* base = (char*)xs + r * 256 + ((15 ^ (r & 7)) << 4);
            *(ushort4*)base = p0;
            *(ushort4*)(base + 8) = z0;
        }
    };

    // ---- prologue: stage first tile ----
    sload_lo(tile); sload_hi(tile);
    swrite(xs0);
    __syncthreads();

    for (int it = 0; tile < ntile; ++it, tile += gridDim.x) {
        unsigned short* xs  = (it & 1) ? xs1 : xs0;
        unsigned short* xsn = (it & 1) ? xs0 : xs1;
        float* yf = (float*)((it & 1) ? (smem + 16384) : smem);
        const int tnext = tile + gridDim.x;
        const bool hn = tnext < ntile;

        // B-frags for the 4 token-tiles of this tile
        bf16x8 bfr[4][4];
        #pragma unroll
        for (int b = 0; b < 4; ++b)
            #pragma unroll
            for (int kk = 0; kk < 4; ++kk) {
                int chunk = kk * 4 + lk;
                bfr[b][kk] = *(const bf16x8*)((const char*)xs + (b * 16 + lrow) * 256 + ((chunk ^ r7) << 4));
            }

        if (hn) sload_lo(tnext);   // issue early: hides under QKV+attn

        // ---- QKV GEMM + attention, head-sequential ----
        #pragma unroll
        for (int hh = 0; hh < 2; ++hh) {
            int h = w + 4 * hh;
            f32x4 acc[3][4];
            #pragma unroll
            for (int part = 0; part < 3; ++part) {
                int u = hh * 3 + part;
                #pragma unroll
                for (int b = 0; b < 4; ++b) {
                    f32x4 a = {0.f, 0.f, 0.f, 0.f};
                    #pragma unroll
                    for (int kk = 0; kk < 4; ++kk)
                        a = __builtin_amdgcn_mfma_f32_16x16x32_bf16(A[u & 1][kk], bfr[b][kk], a, 0, 0, 0);
                    acc[part][b] = a;
                }
                {   // wrap-around prefetch: at u=4,5 loads next iteration's first tiles
                    int vv = (u + 2) % 6;
                    int t2 = (vv % 3) * 8 + (w + 4 * (vv / 3));
                    #pragma unroll
                    for (int kk = 0; kk < 4; ++kk)
                        A[u & 1][kk] = *(const bf16x8*)(W1bp + ((size_t)((t2 * 4 + kk) * 64 + lane)) * 8);
                }
            }
            #pragma unroll
            for (int b = 0; b < 4; ++b) {
                f32x4 Q = acc[0][b], K = acc[1][b], V = acc[2][b];
                float kn0 = __shfl_xor(K[0], 1), kn1 = __shfl_xor(K[1], 1);
                float kn2 = __shfl_xor(K[2], 1), kn3 = __shfl_xor(K[3], 1);
                float ps = Q[0] * K[0] + Q[1] * K[1] + Q[2] * K[2] + Q[3] * K[3];
                float pn = Q[0] * kn0 + Q[1] * kn1 + Q[2] * kn2 + Q[3] * kn3;
                ps += __shfl_xor(ps, 16); ps += __shfl_xor(ps, 32);
                pn += __shfl_xor(pn, 16); pn += __shfl_xor(pn, 32);
                // softmax over 2 logits == sigmoid of scaled difference
                float d = (pn - ps) * scale;
                float p0 = 1.f / (1.f + __expf(d));
                float p1 = 1.f - p0;
                float o0 = p0 * V[0] + p1 * __shfl_xor(V[0], 1);
                float o1 = p0 * V[1] + p1 * __shfl_xor(V[1], 1);
                float o2 = p0 * V[2] + p1 * __shfl_xor(V[2], 1);
                float o3 = p0 * V[3] + p1 * __shfl_xor(V[3], 1);
                unsigned w0 = (unsigned)f2bf(o0) | ((unsigned)f2bf(o1) << 16);
                unsigned w1v = (unsigned)f2bf(o2) | ((unsigned)f2bf(o3) << 16);
                int chunk = 2 * h + (lk >> 1);
                *(uint2*)((char*)obuf + (b * 16 + lrow) * 256 + ((chunk ^ r7) << 4) + (lk & 1) * 8)
                    = make_uint2(w0, w1v);
            }
        }

        if (hn) sload_hi(tnext);   // second half: hides under B2/ofr/outproj
        __syncthreads();   // B2: obuf visible

        bf16x8 ofr[4][4];
        #pragma unroll
        for (int b = 0; b < 4; ++b)
            #pragma unroll
            for (int kk = 0; kk < 4; ++kk) {
                int chunk = kk * 4 + lk;
                ofr[b][kk] = *(const bf16x8*)((const char*)obuf + (b * 16 + lrow) * 256 + ((chunk ^ r7) << 4));
            }
        __syncthreads();   // B2.5: all obuf/xs reads done -> yf region reusable

        // ---- out projection -> yf (f32) ----
        #pragma unroll
        for (int ti = 0; ti < 2; ++ti) {
            int t = w + 4 * ti;
            int chunk = 4 * t + lk;
            #pragma unroll
            for (int b = 0; b < 4; ++b) {
                f32x4 a = {0.f, 0.f, 0.f, 0.f};
                #pragma unroll
                for (int kk = 0; kk < 4; ++kk)
                    a = __builtin_amdgcn_mfma_f32_16x16x32_bf16(A2[ti][kk], ofr[b][kk], a, 0, 0, 0);
                int row = b * 16 + lrow;
                *(f32x4*)((char*)yf + row * 512 + ((chunk ^ r7) << 4)) = a;
            }
        }
        __syncthreads();   // B3: yf visible

        if (hn) swrite(xsn);   // write next tile into the other xs buffer

        // ---- LayerNorm + mean-pool, 8 threads per location ----
        {
            int locl = tid >> 3;
            int s = tid & 7;
            int r0 = 2 * locl, r1 = r0 + 1;
            auto rdf = [&](int r, int c) -> f32x4 {
                return *(const f32x4*)((const char*)yf + r * 512 + ((c ^ (r & 7)) << 4));
            };
            f32x4 v00 = rdf(r0, 2 * s),      v01 = rdf(r0, 2 * s + 1);
            f32x4 v02 = rdf(r0, 16 + 2 * s), v03 = rdf(r0, 16 + 2 * s + 1);
            f32x4 v10 = rdf(r1, 2 * s),      v11 = rdf(r1, 2 * s + 1);
            f32x4 v12 = rdf(r1, 16 + 2 * s), v13 = rdf(r1, 16 + 2 * s + 1);
            __syncthreads();   // B4: yf reads done -> next iter may overwrite obuf/xs
            float a0[16], a1[16];
            #pragma unroll
            for (int j = 0; j < 4; ++j) {
                a0[j] = v00[j]; a0[4 + j] = v01[j]; a0[8 + j] = v02[j]; a0[12 + j] = v03[j];
                a1[j] = v10[j]; a1[4 + j] = v11[j]; a1[8 + j] = v12[j]; a1[12 + j] = v13[j];
            }
            float sum0 = 0.f, sq0 = 0.f, sum1 = 0.f, sq1 = 0.f;
            #pragma unroll
            for (int j = 0; j < 16; ++j) {
                sum0 += a0[j]; sq0 += a0[j] * a0[j];
                sum1 += a1[j]; sq1 += a1[j] * a1[j];
            }
            #pragma unroll
            for (int ww = 1; ww < 8; ww <<= 1) {
                sum0 += __shfl_xor(sum0, ww); sq0 += __shfl_xor(sq0, ww);
                sum1 += __shfl_xor(sum1, ww); sq1 += __shfl_xor(sq1, ww);
            }
            const float inv = 1.f / 120.f;
            float mu0 = sum0 * inv, mu1 = sum1 * inv;
            float var0 = sq0 * inv - mu0 * mu0, var1 = sq1 * inv - mu1 * mu1;
            float rs0 = rsqrtf(var0 + LN_EPS), rs1 = rsqrtf(var1 + LN_EPS);
            float* op = out + (size_t)(tile * 32 + locl) * DD;
            {
                int c = 8 * s;
                #pragma unroll
                for (int q = 0; q < 2; ++q) {
                    f32x4 gm = *(const f32x4*)(gamma + c + 4 * q);
                    f32x4 bt = *(const f32x4*)(beta + c + 4 * q);
                    float4 o4; float z0, z1;
                    z0 = (a0[4 * q + 0] - mu0) * rs0; z1 = (a1[4 * q + 0] - mu1) * rs1;
                    o4.x = 0.5f * (z0 + z1) * gm[0] + bt[0];
                    z0 = (a0[4 * q + 1] - mu0) * rs0; z1 = (a1[4 * q + 1] - mu1) * rs1;
                    o4.y = 0.5f * (z0 + z1) * gm[1] + bt[1];
                    z0 = (a0[4 * q + 2] - mu0) * rs0; z1 = (a1[4 * q + 2] - mu1) * rs1;
                    o4.z = 0.5f * (z0 + z1) * gm[2] + bt[2];
                    z0 = (a0[4 * q + 3] - mu0) * rs0; z1 = (a1[4 * q + 3] - mu1) * rs1;
                    o4.w = 0.5f * (z0 + z1) * gm[3] + bt[3];
                    *(float4*)(op + c + 4 * q) = o4;
                }
            }
            if (s < 7) {
                int c = 64 + 8 * s;
                #pragma unroll
                for (int q = 0; q < 2; ++q) {
                    f32x4 gm = *(const f32x4*)(gamma + c + 4 * q);
                    f32x4 bt = *(const f32x4*)(beta + c + 4 * q);
                    float4 o4; float z0, z1;
                    z0 = (a0[8 + 4 * q + 0] - mu0) * rs0; z1 = (a1[8 + 4 * q + 0] - mu1) * rs1;
                    o4.x = 0.5f * (z0 + z1) * gm[0] + bt[0];
                    z0 = (a0[8 + 4 * q + 1] - mu0) * rs0; z1 = (a1[8 + 4 * q + 1] - mu1) * rs1;
                    o4.y = 0.5f * (z0 + z1) * gm[1] + bt[1];
                    z0 = (a0[8 + 4 * q + 2] - mu0) * rs0; z1 = (a1[8 + 4 * q + 2] - mu1) * rs1;
                    o4.z = 0.5f * (z0 + z1) * gm[2] + bt[2];
                    z0 = (a0[8 + 4 * q + 3] - mu0) * rs0; z1 = (a1[8 + 4 * q + 3] - mu1) * rs1;
                    o4.w = 0.5f * (z0 + z1) * gm[3] + bt[3];
                    *(float4*)(op + c + 4 * q) = o4;
                }
            }
        }
    }
}

extern "C" void kernel_launch(void* const* d_in, const int* in_sizes, int n_in,
                              void* d_out, int out_size, void* d_ws, size_t ws_size,
                              hipStream_t stream) {
    const float* voxel = (const float*)d_in[0];
    const float* cnnf  = (const float*)d_in[1];
    const float* w1    = (const float*)d_in[2];
    const float* b1    = (const float*)d_in[3];
    const float* w2    = (const float*)d_in[4];
    const float* b2    = (const float*)d_in[5];
    const float* gamma = (const float*)d_in[6];
    const float* beta  = (const float*)d_in[7];
    float* out = (float*)d_out;

    unsigned short* W1bp = (unsigned short*)d_ws;                    // 98304 B
    unsigned short* W2bp = (unsigned short*)((char*)d_ws + 98304);   // 32768 B

    int nloc = in_sizes[0] / DD;        // 131072 locations
    int ntile = nloc / 32;              // 4096 tiles of 64 tokens
    int grid = ntile < 768 ? ntile : 768;
    prep_weights<<<128, 256, 0, stream>>>(w1, w2, b1, b2, W1bp, W2bp);
    fused_attn<<<grid, 256, 0, stream>>>(voxel, cnnf, gamma, beta, W1bp, W2bp, out, ntile);
}

// Round 9
// 266.485 us; speedup vs baseline: 1.0351x; 1.0351x over previous
//
#include <hip/hip_runtime.h>
#include <hip/hip_bf16.h>
#include <stdint.h>

#define DD 120
#define HD 15
#define LN_EPS 1e-5f

typedef __attribute__((ext_vector_type(8))) short bf16x8;
typedef __attribute__((ext_vector_type(4))) float f32x4;

__device__ __forceinline__ unsigned short f2bf(float f) {
    return __bfloat16_as_ushort(__float2bfloat16(f));
}

// ---- prep: pack weights as MFMA A-fragments with bias folded into k=120 ----
__global__ void prep_weights(const float* __restrict__ w1, const float* __restrict__ w2,
                             const float* __restrict__ b1, const float* __restrict__ b2,
                             unsigned short* __restrict__ W1bp, unsigned short* __restrict__ W2bp) {
    int idx = blockIdx.x * blockDim.x + threadIdx.x;
    int stride = gridDim.x * blockDim.x;
    for (int p = idx; p < 24 * 4 * 64 * 8; p += stride) {
        int e = p & 7, lane = (p >> 3) & 63, kk = (p >> 9) & 3, t = p >> 11;
        int pos = t * 16 + (lane & 15);
        int part = pos >> 7, rem = pos & 127, h = rem >> 4, i = rem & 15;
        int k = kk * 32 + (lane >> 4) * 8 + e;
        float v = 0.f;
        if (k < DD)        { if (i < HD) v = w1[(part * DD + h * HD + i) * DD + k]; }
        else if (k == DD)  { if (i < HD) v = b1[part * DD + h * HD + i];
                             else if (part == 2 && h == 0) v = 1.0f; }
        W1bp[p] = f2bf(v);
    }
    for (int p = idx; p < 8 * 4 * 64 * 8; p += stride) {
        int e = p & 7, lane = (p >> 3) & 63, kk = (p >> 9) & 3, t = p >> 11;
        int n = t * 16 + (lane & 15);
        int kpad = kk * 32 + (lane >> 4) * 8 + e;
        int i = kpad & 15;
        int h = kpad >> 4;
        float v = 0.f;
        if (n < DD) {
            if (i < HD) v = w2[n * DD + h * HD + i];
            else if (kpad == 15) v = b2[n];
        }
        W2bp[p] = f2bf(v);
    }
}

// staging macros — named float4 vars only, NO arrays/lambdas (R8 spilled via address-taken f[8])
#define SLJ(t_, jj, fj) { int i_ = tid + (jj) * 256;                                   \
    int r_ = i_ / 30, c4_ = i_ % 30; int g_ = (t_) * 64 + r_;                          \
    fj = *(const float4*)(((g_ & 1) ? cnnf : voxel) + (size_t)(g_ >> 1) * DD + c4_ * 4); }
#define SLOAD_LO(t_) { SLJ(t_,0,f0) SLJ(t_,1,f1) SLJ(t_,2,f2) SLJ(t_,3,f3) }
#define SLOAD_HI(t_) { SLJ(t_,4,f4) SLJ(t_,5,f5) SLJ(t_,6,f6) if (tid < 128) SLJ(t_,7,f7) }
#define SWJ(xs_, jj, fj) { int i_ = tid + (jj) * 256;                                  \
    int r_ = i_ / 30, c4_ = i_ % 30;                                                   \
    ushort4 hv_; hv_.x = f2bf(fj.x); hv_.y = f2bf(fj.y);                               \
    hv_.z = f2bf(fj.z); hv_.w = f2bf(fj.w);                                            \
    int c8_ = c4_ >> 1, sub_ = (c4_ & 1) * 8;                                          \
    *(ushort4*)((char*)(xs_) + r_ * 256 + ((c8_ ^ (r_ & 7)) << 4) + sub_) = hv_; }
#define SWRITE(xs_) {                                                                  \
    SWJ(xs_,0,f0) SWJ(xs_,1,f1) SWJ(xs_,2,f2) SWJ(xs_,3,f3)                            \
    SWJ(xs_,4,f4) SWJ(xs_,5,f5) SWJ(xs_,6,f6) if (tid < 128) { SWJ(xs_,7,f7) }         \
    if (tid < 64) { int r_ = tid;                                                      \
        ushort4 p0_; p0_.x = 0x3F80; p0_.y = 0; p0_.z = 0; p0_.w = 0;                  \
        ushort4 z0_; z0_.x = 0; z0_.y = 0; z0_.z = 0; z0_.w = 0;                       \
        char* base_ = (char*)(xs_) + r_ * 256 + ((15 ^ (r_ & 7)) << 4);                \
        *(ushort4*)base_ = p0_; *(ushort4*)(base_ + 8) = z0_; } }

// ---- fused, persistent multi-tile, double-buffered staging (reg-pipelined) ----
__global__ __launch_bounds__(256, 3) void fused_attn(
    const float* __restrict__ voxel, const float* __restrict__ cnnf,
    const float* __restrict__ gamma, const float* __restrict__ beta,
    const unsigned short* __restrict__ W1bp, const unsigned short* __restrict__ W2bp,
    float* __restrict__ out, int ntile)
{
    // layout: [xs0 16K][obuf 16K][xs1 16K]
    // parity 0: cur=xs0, yf = smem+0     (xs0+obuf, contiguous 32K f32)
    // parity 1: cur=xs1, yf = smem+16384 (obuf+xs1)
    __shared__ __align__(16) char smem[49152];
    unsigned short* xs0  = (unsigned short*)smem;
    unsigned short* obuf = (unsigned short*)(smem + 16384);
    unsigned short* xs1  = (unsigned short*)(smem + 32768);

    const int tid = threadIdx.x;
    const int wave = tid >> 6, lane = tid & 63;
    const int lrow = lane & 15, lk = lane >> 4;
    const int w = wave;
    const int r7 = lrow & 7;
    const float scale = 0.25819888974716112567f;   // 1/sqrt(15)

    // W1 streaming buffers: A[0]=tile w, A[1]=tile 8+w (wrap-prefetched, stay warm)
    bf16x8 A[2][4];
    #pragma unroll
    for (int kk = 0; kk < 4; ++kk) {
        A[0][kk] = *(const bf16x8*)(W1bp + ((size_t)(((w) * 4 + kk) * 64 + lane)) * 8);
        A[1][kk] = *(const bf16x8*)(W1bp + ((size_t)(((8 + w) * 4 + kk) * 64 + lane)) * 8);
    }

    float4 f0, f1, f2, f3, f4, f5, f6, f7;
    int tile = blockIdx.x;

    // ---- prologue: stage first tile ----
    SLOAD_LO(tile) SLOAD_HI(tile)
    SWRITE(xs0)
    __syncthreads();

    for (int it = 0; tile < ntile; ++it, tile += gridDim.x) {
        unsigned short* xs  = (it & 1) ? xs1 : xs0;
        unsigned short* xsn = (it & 1) ? xs0 : xs1;
        float* yf = (float*)((it & 1) ? (smem + 16384) : smem);
        const int tnext = tile + gridDim.x;
        const bool hn = tnext < ntile;

        // B-frags for the 4 token-tiles of this tile
        bf16x8 bfr[4][4];
        #pragma unroll
        for (int b = 0; b < 4; ++b)
            #pragma unroll
            for (int kk = 0; kk < 4; ++kk) {
                int chunk = kk * 4 + lk;
                bfr[b][kk] = *(const bf16x8*)((const char*)xs + (b * 16 + lrow) * 256 + ((chunk ^ r7) << 4));
            }

        if (hn) { SLOAD_LO(tnext) }   // issue early: hides under QKV+attn

        // ---- QKV GEMM + attention, head-sequential ----
        #pragma unroll
        for (int hh = 0; hh < 2; ++hh) {
            int h = w + 4 * hh;
            f32x4 acc[3][4];
            #pragma unroll
            for (int part = 0; part < 3; ++part) {
                int u = hh * 3 + part;
                #pragma unroll
                for (int b = 0; b < 4; ++b) {
                    f32x4 a = {0.f, 0.f, 0.f, 0.f};
                    #pragma unroll
                    for (int kk = 0; kk < 4; ++kk)
                        a = __builtin_amdgcn_mfma_f32_16x16x32_bf16(A[u & 1][kk], bfr[b][kk], a, 0, 0, 0);
                    acc[part][b] = a;
                }
                {   // wrap-around prefetch: at u=4,5 loads next iteration's first tiles
                    int vv = (u + 2) % 6;
                    int t2 = (vv % 3) * 8 + (w + 4 * (vv / 3));
                    #pragma unroll
                    for (int kk = 0; kk < 4; ++kk)
                        A[u & 1][kk] = *(const bf16x8*)(W1bp + ((size_t)((t2 * 4 + kk) * 64 + lane)) * 8);
                }
            }
            #pragma unroll
            for (int b = 0; b < 4; ++b) {
                f32x4 Q = acc[0][b], K = acc[1][b], V = acc[2][b];
                float kn0 = __shfl_xor(K[0], 1), kn1 = __shfl_xor(K[1], 1);
                float kn2 = __shfl_xor(K[2], 1), kn3 = __shfl_xor(K[3], 1);
                float ps = Q[0] * K[0] + Q[1] * K[1] + Q[2] * K[2] + Q[3] * K[3];
                float pn = Q[0] * kn0 + Q[1] * kn1 + Q[2] * kn2 + Q[3] * kn3;
                ps += __shfl_xor(ps, 16); ps += __shfl_xor(ps, 32);
                pn += __shfl_xor(pn, 16); pn += __shfl_xor(pn, 32);
                float d = (pn - ps) * scale;
                float p0 = 1.f / (1.f + __expf(d));
                float p1 = 1.f - p0;
                float o0 = p0 * V[0] + p1 * __shfl_xor(V[0], 1);
                float o1 = p0 * V[1] + p1 * __shfl_xor(V[1], 1);
                float o2 = p0 * V[2] + p1 * __shfl_xor(V[2], 1);
                float o3 = p0 * V[3] + p1 * __shfl_xor(V[3], 1);
                unsigned w0 = (unsigned)f2bf(o0) | ((unsigned)f2bf(o1) << 16);
                unsigned w1v = (unsigned)f2bf(o2) | ((unsigned)f2bf(o3) << 16);
                int chunk = 2 * h + (lk >> 1);
                *(uint2*)((char*)obuf + (b * 16 + lrow) * 256 + ((chunk ^ r7) << 4) + (lk & 1) * 8)
                    = make_uint2(w0, w1v);
            }
        }

        if (hn) { SLOAD_HI(tnext) }   // hides under B2/ofr/outproj

        // W2 A-frags per iteration (L2-hit refetch; keeps QKV-phase VGPR peak low)
        bf16x8 A2[2][4];
        #pragma unroll
        for (int ti = 0; ti < 2; ++ti)
            #pragma unroll
            for (int kk = 0; kk < 4; ++kk)
                A2[ti][kk] = *(const bf16x8*)(W2bp + ((size_t)(((w + 4 * ti) * 4 + kk) * 64 + lane)) * 8);
        __syncthreads();   // B2: obuf visible

        bf16x8 ofr[4][4];
        #pragma unroll
        for (int b = 0; b < 4; ++b)
            #pragma unroll
            for (int kk = 0; kk < 4; ++kk) {
                int chunk = kk * 4 + lk;
                ofr[b][kk] = *(const bf16x8*)((const char*)obuf + (b * 16 + lrow) * 256 + ((chunk ^ r7) << 4));
            }
        __syncthreads();   // B2.5: all obuf/xs reads done -> yf region reusable

        // ---- out projection -> yf (f32) ----
        #pragma unroll
        for (int ti = 0; ti < 2; ++ti) {
            int t = w + 4 * ti;
            int chunk = 4 * t + lk;
            #pragma unroll
            for (int b = 0; b < 4; ++b) {
                f32x4 a = {0.f, 0.f, 0.f, 0.f};
                #pragma unroll
                for (int kk = 0; kk < 4; ++kk)
                    a = __builtin_amdgcn_mfma_f32_16x16x32_bf16(A2[ti][kk], ofr[b][kk], a, 0, 0, 0);
                int row = b * 16 + lrow;
                *(f32x4*)((char*)yf + row * 512 + ((chunk ^ r7) << 4)) = a;
            }
        }
        __syncthreads();   // B3: yf visible

        if (hn) { SWRITE(xsn) }   // write next tile into the other xs buffer

        // ---- LayerNorm + mean-pool, 8 threads per location ----
        {
            int locl = tid >> 3;
            int s = tid & 7;
            int r0 = 2 * locl, r1 = r0 + 1;
            auto rdf = [&](int r, int c) -> f32x4 {
                return *(const f32x4*)((const char*)yf + r * 512 + ((c ^ (r & 7)) << 4));
            };
            f32x4 v00 = rdf(r0, 2 * s),      v01 = rdf(r0, 2 * s + 1);
            f32x4 v02 = rdf(r0, 16 + 2 * s), v03 = rdf(r0, 16 + 2 * s + 1);
            f32x4 v10 = rdf(r1, 2 * s),      v11 = rdf(r1, 2 * s + 1);
            f32x4 v12 = rdf(r1, 16 + 2 * s), v13 = rdf(r1, 16 + 2 * s + 1);
            __syncthreads();   // B4: yf reads done; swrite also ordered for next iter
            float a0[16], a1[16];
            #pragma unroll
            for (int j = 0; j < 4; ++j) {
                a0[j] = v00[j]; a0[4 + j] = v01[j]; a0[8 + j] = v02[j]; a0[12 + j] = v03[j];
                a1[j] = v10[j]; a1[4 + j] = v11[j]; a1[8 + j] = v12[j]; a1[12 + j] = v13[j];
            }
            float sum0 = 0.f, sq0 = 0.f, sum1 = 0.f, sq1 = 0.f;
            #pragma unroll
            for (int j = 0; j < 16; ++j) {
                sum0 += a0[j]; sq0 += a0[j] * a0[j];
                sum1 += a1[j]; sq1 += a1[j] * a1[j];
            }
            #pragma unroll
            for (int ww = 1; ww < 8; ww <<= 1) {
                sum0 += __shfl_xor(sum0, ww); sq0 += __shfl_xor(sq0, ww);
                sum1 += __shfl_xor(sum1, ww); sq1 += __shfl_xor(sq1, ww);
            }
            const float inv = 1.f / 120.f;
            float mu0 = sum0 * inv, mu1 = sum1 * inv;
            float var0 = sq0 * inv - mu0 * mu0, var1 = sq1 * inv - mu1 * mu1;
            float rs0 = rsqrtf(var0 + LN_EPS), rs1 = rsqrtf(var1 + LN_EPS);
            float* op = out + (size_t)(tile * 32 + locl) * DD;
            {
                int c = 8 * s;
                #pragma unroll
                for (int q = 0; q < 2; ++q) {
                    f32x4 gm = *(const f32x4*)(gamma + c + 4 * q);
                    f32x4 bt = *(const f32x4*)(beta + c + 4 * q);
                    float4 o4; float z0, z1;
                    z0 = (a0[4 * q + 0] - mu0) * rs0; z1 = (a1[4 * q + 0] - mu1) * rs1;
                    o4.x = 0.5f * (z0 + z1) * gm[0] + bt[0];
                    z0 = (a0[4 * q + 1] - mu0) * rs0; z1 = (a1[4 * q + 1] - mu1) * rs1;
                    o4.y = 0.5f * (z0 + z1) * gm[1] + bt[1];
                    z0 = (a0[4 * q + 2] - mu0) * rs0; z1 = (a1[4 * q + 2] - mu1) * rs1;
                    o4.z = 0.5f * (z0 + z1) * gm[2] + bt[2];
                    z0 = (a0[4 * q + 3] - mu0) * rs0; z1 = (a1[4 * q + 3] - mu1) * rs1;
                    o4.w = 0.5f * (z0 + z1) * gm[3] + bt[3];
                    *(float4*)(op + c + 4 * q) = o4;
                }
            }
            if (s < 7) {
                int c = 64 + 8 * s;
                #pragma unroll
                for (int q = 0; q < 2; ++q) {
                    f32x4 gm = *(const f32x4*)(gamma + c + 4 * q);
                    f32x4 bt = *(const f32x4*)(beta + c + 4 * q);
                    float4 o4; float z0, z1;
                    z0 = (a0[8 + 4 * q + 0] - mu0) * rs0; z1 = (a1[8 + 4 * q + 0] - mu1) * rs1;
                    o4.x = 0.5f * (z0 + z1) * gm[0] + bt[0];
                    z0 = (a0[8 + 4 * q + 1] - mu0) * rs0; z1 = (a1[8 + 4 * q + 1] - mu1) * rs1;
                    o4.y = 0.5f * (z0 + z1) * gm[1] + bt[1];
                    z0 = (a0[8 + 4 * q + 2] - mu0) * rs0; z1 = (a1[8 + 4 * q + 2] - mu1) * rs1;
                    o4.z = 0.5f * (z0 + z1) * gm[2] + bt[2];
                    z0 = (a0[8 + 4 * q + 3] - mu0) * rs0; z1 = (a1[8 + 4 * q + 3] - mu1) * rs1;
                    o4.w = 0.5f * (z0 + z1) * gm[3] + bt[3];
                    *(float4*)(op + c + 4 * q) = o4;
                }
            }
        }
    }
}

extern "C" void kernel_launch(void* const* d_in, const int* in_sizes, int n_in,
                              void* d_out, int out_size, void* d_ws, size_t ws_size,
                              hipStream_t stream) {
    const float* voxel = (const float*)d_in[0];
    const float* cnnf  = (const float*)d_in[1];
    const float* w1    = (const float*)d_in[2];
    const float* b1    = (const float*)d_in[3];
    const float* w2    = (const float*)d_in[4];
    const float* b2    = (const float*)d_in[5];
    const float* gamma = (const float*)d_in[6];
    const float* beta  = (const float*)d_in[7];
    float* out = (float*)d_out;

    unsigned short* W1bp = (unsigned short*)d_ws;                    // 98304 B
    unsigned short* W2bp = (unsigned short*)((char*)d_ws + 98304);   // 32768 B

    int nloc = in_sizes[0] / DD;        // 131072 locations
    int ntile = nloc / 32;              // 4096 tiles of 64 tokens
    int grid = ntile < 768 ? ntile : 768;
    prep_weights<<<128, 256, 0, stream>>>(w1, w2, b1, b2, W1bp, W2bp);
    fused_attn<<<grid, 256, 0, stream>>>(voxel, cnnf, gamma, beta, W1bp, W2bp, out, ntile);
}

// Round 10
// 266.037 us; speedup vs baseline: 1.0369x; 1.0017x over previous
//
#include <hip/hip_runtime.h>
#include <hip/hip_bf16.h>
#include <stdint.h>

#define DD 120
#define HD 15
#define LN_EPS 1e-5f

typedef __attribute__((ext_vector_type(8))) short bf16x8;
typedef __attribute__((ext_vector_type(4))) float f32x4;

__device__ __forceinline__ unsigned short f2bf(float f) {
    return __bfloat16_as_ushort(__float2bfloat16(f));
}

// ---- prep: pack weights as MFMA A-fragments with bias folded into k=120 ----
__global__ void prep_weights(const float* __restrict__ w1, const float* __restrict__ w2,
                             const float* __restrict__ b1, const float* __restrict__ b2,
                             unsigned short* __restrict__ W1bp, unsigned short* __restrict__ W2bp) {
    int idx = blockIdx.x * blockDim.x + threadIdx.x;
    int stride = gridDim.x * blockDim.x;
    for (int p = idx; p < 24 * 4 * 64 * 8; p += stride) {
        int e = p & 7, lane = (p >> 3) & 63, kk = (p >> 9) & 3, t = p >> 11;
        int pos = t * 16 + (lane & 15);
        int part = pos >> 7, rem = pos & 127, h = rem >> 4, i = rem & 15;
        int k = kk * 32 + (lane >> 4) * 8 + e;
        float v = 0.f;
        if (k < DD)        { if (i < HD) v = w1[(part * DD + h * HD + i) * DD + k]; }
        else if (k == DD)  { if (i < HD) v = b1[part * DD + h * HD + i];
                             else if (part == 2 && h == 0) v = 1.0f; }
        W1bp[p] = f2bf(v);
    }
    for (int p = idx; p < 8 * 4 * 64 * 8; p += stride) {
        int e = p & 7, lane = (p >> 3) & 63, kk = (p >> 9) & 3, t = p >> 11;
        int n = t * 16 + (lane & 15);
        int kpad = kk * 32 + (lane >> 4) * 8 + e;
        int i = kpad & 15;
        int h = kpad >> 4;
        float v = 0.f;
        if (n < DD) {
            if (i < HD) v = w2[n * DD + h * HD + i];
            else if (kpad == 15) v = b2[n];
        }
        W2bp[p] = f2bf(v);
    }
}

// staging macros — named float4 vars, no arrays (keep liveness register-friendly)
#define SLJ(t_, jj, fj) { int i_ = tid + (jj) * 256;                                   \
    int r_ = i_ / 30, c4_ = i_ % 30; int g_ = (t_) * 64 + r_;                          \
    fj = *(const float4*)(((g_ & 1) ? cnnf : voxel) + (size_t)(g_ >> 1) * DD + c4_ * 4); }
#define SLOAD_LO(t_) { SLJ(t_,0,f0) SLJ(t_,1,f1) SLJ(t_,2,f2) SLJ(t_,3,f3) }
#define SLOAD_HI(t_) { SLJ(t_,4,f4) SLJ(t_,5,f5) SLJ(t_,6,f6) if (tid < 128) SLJ(t_,7,f7) }
#define SWJ(xs_, jj, fj) { int i_ = tid + (jj) * 256;                                  \
    int r_ = i_ / 30, c4_ = i_ % 30;                                                   \
    ushort4 hv_; hv_.x = f2bf(fj.x); hv_.y = f2bf(fj.y);                               \
    hv_.z = f2bf(fj.z); hv_.w = f2bf(fj.w);                                            \
    int c8_ = c4_ >> 1, sub_ = (c4_ & 1) * 8;                                          \
    *(ushort4*)((char*)(xs_) + r_ * 256 + ((c8_ ^ (r_ & 7)) << 4) + sub_) = hv_; }
#define SWRITE(xs_) {                                                                  \
    SWJ(xs_,0,f0) SWJ(xs_,1,f1) SWJ(xs_,2,f2) SWJ(xs_,3,f3)                            \
    SWJ(xs_,4,f4) SWJ(xs_,5,f5) SWJ(xs_,6,f6) if (tid < 128) { SWJ(xs_,7,f7) }         \
    if (tid < 64) { int r_ = tid;                                                      \
        ushort4 p0_; p0_.x = 0x3F80; p0_.y = 0; p0_.z = 0; p0_.w = 0;                  \
        ushort4 z0_; z0_.x = 0; z0_.y = 0; z0_.z = 0; z0_.w = 0;                       \
        char* base_ = (char*)(xs_) + r_ * 256 + ((15 ^ (r_ & 7)) << 4);                \
        *(ushort4*)base_ = p0_; *(ushort4*)(base_ + 8) = z0_; } }

// ---- fused, persistent multi-tile, double-buffered staging (reg-pipelined) ----
// waves_per_eu pinned to (3,3): LDS 48KB caps at 3 WG/CU anyway; without the max
// pin the allocator targeted 6 waves/EU (VGPR=84) and spilled f0..f7 to scratch
// (R8/R9: FETCH 475MB, WRITE +268MB = exactly one f0..f7 round-trip per iter).
__global__ __attribute__((amdgpu_flat_work_group_size(256, 256), amdgpu_waves_per_eu(3, 3)))
void fused_attn(
    const float* __restrict__ voxel, const float* __restrict__ cnnf,
    const float* __restrict__ gamma, const float* __restrict__ beta,
    const unsigned short* __restrict__ W1bp, const unsigned short* __restrict__ W2bp,
    float* __restrict__ out, int ntile)
{
    // layout: [xs0 16K][obuf 16K][xs1 16K]
    // parity 0: cur=xs0, yf = smem+0     (xs0+obuf, contiguous 32K f32)
    // parity 1: cur=xs1, yf = smem+16384 (obuf+xs1)
    __shared__ __align__(16) char smem[49152];
    unsigned short* xs0  = (unsigned short*)smem;
    unsigned short* obuf = (unsigned short*)(smem + 16384);
    unsigned short* xs1  = (unsigned short*)(smem + 32768);

    const int tid = threadIdx.x;
    const int wave = tid >> 6, lane = tid & 63;
    const int lrow = lane & 15, lk = lane >> 4;
    const int w = wave;
    const int r7 = lrow & 7;
    const float scale = 0.25819888974716112567f;   // 1/sqrt(15)

    // W1 streaming buffers: A[0]=tile w, A[1]=tile 8+w (wrap-prefetched, stay warm)
    bf16x8 A[2][4];
    #pragma unroll
    for (int kk = 0; kk < 4; ++kk) {
        A[0][kk] = *(const bf16x8*)(W1bp + ((size_t)(((w) * 4 + kk) * 64 + lane)) * 8);
        A[1][kk] = *(const bf16x8*)(W1bp + ((size_t)(((8 + w) * 4 + kk) * 64 + lane)) * 8);
    }

    float4 f0, f1, f2, f3, f4, f5, f6, f7;
    int tile = blockIdx.x;

    // ---- prologue: stage first tile ----
    SLOAD_LO(tile) SLOAD_HI(tile)
    SWRITE(xs0)
    __syncthreads();

    for (int it = 0; tile < ntile; ++it, tile += gridDim.x) {
        unsigned short* xs  = (it & 1) ? xs1 : xs0;
        unsigned short* xsn = (it & 1) ? xs0 : xs1;
        float* yf = (float*)((it & 1) ? (smem + 16384) : smem);
        const int tnext = tile + gridDim.x;
        const bool hn = tnext < ntile;

        // B-frags for the 4 token-tiles of this tile
        bf16x8 bfr[4][4];
        #pragma unroll
        for (int b = 0; b < 4; ++b)
            #pragma unroll
            for (int kk = 0; kk < 4; ++kk) {
                int chunk = kk * 4 + lk;
                bfr[b][kk] = *(const bf16x8*)((const char*)xs + (b * 16 + lrow) * 256 + ((chunk ^ r7) << 4));
            }

        if (hn) { SLOAD_LO(tnext) }   // issue early: hides under QKV+attn

        // ---- QKV GEMM + attention, head-sequential ----
        #pragma unroll
        for (int hh = 0; hh < 2; ++hh) {
            int h = w + 4 * hh;
            f32x4 acc[3][4];
            #pragma unroll
            for (int part = 0; part < 3; ++part) {
                int u = hh * 3 + part;
                #pragma unroll
                for (int b = 0; b < 4; ++b) {
                    f32x4 a = {0.f, 0.f, 0.f, 0.f};
                    #pragma unroll
                    for (int kk = 0; kk < 4; ++kk)
                        a = __builtin_amdgcn_mfma_f32_16x16x32_bf16(A[u & 1][kk], bfr[b][kk], a, 0, 0, 0);
                    acc[part][b] = a;
                }
                {   // wrap-around prefetch: at u=4,5 loads next iteration's first tiles
                    int vv = (u + 2) % 6;
                    int t2 = (vv % 3) * 8 + (w + 4 * (vv / 3));
                    #pragma unroll
                    for (int kk = 0; kk < 4; ++kk)
                        A[u & 1][kk] = *(const bf16x8*)(W1bp + ((size_t)((t2 * 4 + kk) * 64 + lane)) * 8);
                }
            }
            #pragma unroll
            for (int b = 0; b < 4; ++b) {
                f32x4 Q = acc[0][b], K = acc[1][b], V = acc[2][b];
                float kn0 = __shfl_xor(K[0], 1), kn1 = __shfl_xor(K[1], 1);
                float kn2 = __shfl_xor(K[2], 1), kn3 = __shfl_xor(K[3], 1);
                float ps = Q[0] * K[0] + Q[1] * K[1] + Q[2] * K[2] + Q[3] * K[3];
                float pn = Q[0] * kn0 + Q[1] * kn1 + Q[2] * kn2 + Q[3] * kn3;
                ps += __shfl_xor(ps, 16); ps += __shfl_xor(ps, 32);
                pn += __shfl_xor(pn, 16); pn += __shfl_xor(pn, 32);
                float d = (pn - ps) * scale;
                float p0 = 1.f / (1.f + __expf(d));
                float p1 = 1.f - p0;
                float o0 = p0 * V[0] + p1 * __shfl_xor(V[0], 1);
                float o1 = p0 * V[1] + p1 * __shfl_xor(V[1], 1);
                float o2 = p0 * V[2] + p1 * __shfl_xor(V[2], 1);
                float o3 = p0 * V[3] + p1 * __shfl_xor(V[3], 1);
                unsigned w0 = (unsigned)f2bf(o0) | ((unsigned)f2bf(o1) << 16);
                unsigned w1v = (unsigned)f2bf(o2) | ((unsigned)f2bf(o3) << 16);
                int chunk = 2 * h + (lk >> 1);
                *(uint2*)((char*)obuf + (b * 16 + lrow) * 256 + ((chunk ^ r7) << 4) + (lk & 1) * 8)
                    = make_uint2(w0, w1v);
            }
        }

        if (hn) { SLOAD_HI(tnext) }   // hides under B2/ofr/outproj

        // W2 A-frags per iteration (L2-hit refetch; keeps QKV-phase VGPR peak low)
        bf16x8 A2[2][4];
        #pragma unroll
        for (int ti = 0; ti < 2; ++ti)
            #pragma unroll
            for (int kk = 0; kk < 4; ++kk)
                A2[ti][kk] = *(const bf16x8*)(W2bp + ((size_t)(((w + 4 * ti) * 4 + kk) * 64 + lane)) * 8);
        __syncthreads();   // B2: obuf visible

        bf16x8 ofr[4][4];
        #pragma unroll
        for (int b = 0; b < 4; ++b)
            #pragma unroll
            for (int kk = 0; kk < 4; ++kk) {
                int chunk = kk * 4 + lk;
                ofr[b][kk] = *(const bf16x8*)((const char*)obuf + (b * 16 + lrow) * 256 + ((chunk ^ r7) << 4));
            }
        __syncthreads();   // B2.5: all obuf/xs reads done -> yf region reusable

        // ---- out projection -> yf (f32) ----
        #pragma unroll
        for (int ti = 0; ti < 2; ++ti) {
            int t = w + 4 * ti;
            int chunk = 4 * t + lk;
            #pragma unroll
            for (int b = 0; b < 4; ++b) {
                f32x4 a = {0.f, 0.f, 0.f, 0.f};
                #pragma unroll
                for (int kk = 0; kk < 4; ++kk)
                    a = __builtin_amdgcn_mfma_f32_16x16x32_bf16(A2[ti][kk], ofr[b][kk], a, 0, 0, 0);
                int row = b * 16 + lrow;
                *(f32x4*)((char*)yf + row * 512 + ((chunk ^ r7) << 4)) = a;
            }
        }
        __syncthreads();   // B3: yf visible

        if (hn) { SWRITE(xsn) }   // write next tile into the other xs buffer

        // ---- LayerNorm + mean-pool, 8 threads per location ----
        {
            int locl = tid >> 3;
            int s = tid & 7;
            int r0 = 2 * locl, r1 = r0 + 1;
            auto rdf = [&](int r, int c) -> f32x4 {
                return *(const f32x4*)((const char*)yf + r * 512 + ((c ^ (r & 7)) << 4));
            };
            f32x4 v00 = rdf(r0, 2 * s),      v01 = rdf(r0, 2 * s + 1);
            f32x4 v02 = rdf(r0, 16 + 2 * s), v03 = rdf(r0, 16 + 2 * s + 1);
            f32x4 v10 = rdf(r1, 2 * s),      v11 = rdf(r1, 2 * s + 1);
            f32x4 v12 = rdf(r1, 16 + 2 * s), v13 = rdf(r1, 16 + 2 * s + 1);
            __syncthreads();   // B4: yf reads done; next iter may overwrite obuf/xs
            float a0[16], a1[16];
            #pragma unroll
            for (int j = 0; j < 4; ++j) {
                a0[j] = v00[j]; a0[4 + j] = v01[j]; a0[8 + j] = v02[j]; a0[12 + j] = v03[j];
                a1[j] = v10[j]; a1[4 + j] = v11[j]; a1[8 + j] = v12[j]; a1[12 + j] = v13[j];
            }
            float sum0 = 0.f, sq0 = 0.f, sum1 = 0.f, sq1 = 0.f;
            #pragma unroll
            for (int j = 0; j < 16; ++j) {
                sum0 += a0[j]; sq0 += a0[j] * a0[j];
                sum1 += a1[j]; sq1 += a1[j] * a1[j];
            }
            #pragma unroll
            for (int ww = 1; ww < 8; ww <<= 1) {
                sum0 += __shfl_xor(sum0, ww); sq0 += __shfl_xor(sq0, ww);
                sum1 += __shfl_xor(sum1, ww); sq1 += __shfl_xor(sq1, ww);
            }
            const float inv = 1.f / 120.f;
            float mu0 = sum0 * inv, mu1 = sum1 * inv;
            float var0 = sq0 * inv - mu0 * mu0, var1 = sq1 * inv - mu1 * mu1;
            float rs0 = rsqrtf(var0 + LN_EPS), rs1 = rsqrtf(var1 + LN_EPS);
            float* op = out + (size_t)(tile * 32 + locl) * DD;
            {
                int c = 8 * s;
                #pragma unroll
                for (int q = 0; q < 2; ++q) {
                    f32x4 gm = *(const f32x4*)(gamma + c + 4 * q);
                    f32x4 bt = *(const f32x4*)(beta + c + 4 * q);
                    float4 o4; float z0, z1;
                    z0 = (a0[4 * q + 0] - mu0) * rs0; z1 = (a1[4 * q + 0] - mu1) * rs1;
                    o4.x = 0.5f * (z0 + z1) * gm[0] + bt[0];
                    z0 = (a0[4 * q + 1] - mu0) * rs0; z1 = (a1[4 * q + 1] - mu1) * rs1;
                    o4.y = 0.5f * (z0 + z1) * gm[1] + bt[1];
                    z0 = (a0[4 * q + 2] - mu0) * rs0; z1 = (a1[4 * q + 2] - mu1) * rs1;
                    o4.z = 0.5f * (z0 + z1) * gm[2] + bt[2];
                    z0 = (a0[4 * q + 3] - mu0) * rs0; z1 = (a1[4 * q + 3] - mu1) * rs1;
                    o4.w = 0.5f * (z0 + z1) * gm[3] + bt[3];
                    *(float4*)(op + c + 4 * q) = o4;
                }
            }
            if (s < 7) {
                int c = 64 + 8 * s;
                #pragma unroll
                for (int q = 0; q < 2; ++q) {
                    f32x4 gm = *(const f32x4*)(gamma + c + 4 * q);
                    f32x4 bt = *(const f32x4*)(beta + c + 4 * q);
                    float4 o4; float z0, z1;
                    z0 = (a0[8 + 4 * q + 0] - mu0) * rs0; z1 = (a1[8 + 4 * q + 0] - mu1) * rs1;
                    o4.x = 0.5f * (z0 + z1) * gm[0] + bt[0];
                    z0 = (a0[8 + 4 * q + 1] - mu0) * rs0; z1 = (a1[8 + 4 * q + 1] - mu1) * rs1;
                    o4.y = 0.5f * (z0 + z1) * gm[1] + bt[1];
                    z0 = (a0[8 + 4 * q + 2] - mu0) * rs0; z1 = (a1[8 + 4 * q + 2] - mu1) * rs1;
                    o4.z = 0.5f * (z0 + z1) * gm[2] + bt[2];
                    z0 = (a0[8 + 4 * q + 3] - mu0) * rs0; z1 = (a1[8 + 4 * q + 3] - mu1) * rs1;
                    o4.w = 0.5f * (z0 + z1) * gm[3] + bt[3];
                    *(float4*)(op + c + 4 * q) = o4;
                }
            }
        }
    }
}

extern "C" void kernel_launch(void* const* d_in, const int* in_sizes, int n_in,
                              void* d_out, int out_size, void* d_ws, size_t ws_size,
                              hipStream_t stream) {
    const float* voxel = (const float*)d_in[0];
    const float* cnnf  = (const float*)d_in[1];
    const float* w1    = (const float*)d_in[2];
    const float* b1    = (const float*)d_in[3];
    const float* w2    = (const float*)d_in[4];
    const float* b2    = (const float*)d_in[5];
    const float* gamma = (const float*)d_in[6];
    const float* beta  = (const float*)d_in[7];
    float* out = (float*)d_out;

    unsigned short* W1bp = (unsigned short*)d_ws;                    // 98304 B
    unsigned short* W2bp = (unsigned short*)((char*)d_ws + 98304);   // 32768 B

    int nloc = in_sizes[0] / DD;        // 131072 locations
    int ntile = nloc / 32;              // 4096 tiles of 64 tokens
    int grid = ntile < 768 ? ntile : 768;
    prep_weights<<<128, 256, 0, stream>>>(w1, w2, b1, b2, W1bp, W2bp);
    fused_attn<<<grid, 256, 0, stream>>>(voxel, cnnf, gamma, beta, W1bp, W2bp, out, ntile);
}

// Round 12
// 81.138 us; speedup vs baseline: 3.3997x; 3.2788x over previous
//
#include <hip/hip_runtime.h>
#include <hip/hip_bf16.h>
#include <stdint.h>

#define DD 120
#define HD 15
#define LN_EPS 1e-5f

typedef __attribute__((ext_vector_type(8))) short bf16x8;
typedef __attribute__((ext_vector_type(4))) float f32x4;

__device__ __forceinline__ unsigned short f2bf(float f) {
    return __bfloat16_as_ushort(__float2bfloat16(f));
}

// ---- prep: pack weights as MFMA A-fragments with bias folded into k=120 ----
// W1bp: [24 t][4 kk][64 lane][8 e]; A-row n = padded qkv channel t*16+(lane&15)
//       tile t = part*8 + h (pos = part*128 + h*16 + i)
//       k<120: weight; k==120: bias (i<15) / 1.0 marker for V-head0-pad (part==2,h==0,i==15)
// W2bp: [8 t][4 kk][64 lane][8 e]; A-row n = out channel; k = head-padded o-channel;
//       kpad==15 carries out_b (fed by O[15]==1.0)
__global__ void prep_weights(const float* __restrict__ w1, const float* __restrict__ w2,
                             const float* __restrict__ b1, const float* __restrict__ b2,
                             unsigned short* __restrict__ W1bp, unsigned short* __restrict__ W2bp) {
    int idx = blockIdx.x * blockDim.x + threadIdx.x;
    int stride = gridDim.x * blockDim.x;
    for (int p = idx; p < 24 * 4 * 64 * 8; p += stride) {
        int e = p & 7, lane = (p >> 3) & 63, kk = (p >> 9) & 3, t = p >> 11;
        int pos = t * 16 + (lane & 15);
        int part = pos >> 7, rem = pos & 127, h = rem >> 4, i = rem & 15;
        int k = kk * 32 + (lane >> 4) * 8 + e;
        float v = 0.f;
        if (k < DD)        { if (i < HD) v = w1[(part * DD + h * HD + i) * DD + k]; }
        else if (k == DD)  { if (i < HD) v = b1[part * DD + h * HD + i];
                             else if (part == 2 && h == 0) v = 1.0f; }
        W1bp[p] = f2bf(v);
    }
    for (int p = idx; p < 8 * 4 * 64 * 8; p += stride) {
        int e = p & 7, lane = (p >> 3) & 63, kk = (p >> 9) & 3, t = p >> 11;
        int n = t * 16 + (lane & 15);
        int kpad = kk * 32 + (lane >> 4) * 8 + e;
        int i = kpad & 15;
        int h = kpad >> 4;
        float v = 0.f;
        if (n < DD) {
            if (i < HD) v = w2[n * DD + h * HD + i];
            else if (kpad == 15) v = b2[n];
        }
        W2bp[p] = f2bf(v);
    }
}

// ---- fused: 32 locations (64 tokens) per 256-thread WG; 4-way n-split ----
// Exact R7 structure (known-good 83.3us, absmax 0.03125) + s_setprio(1) around
// MFMA clusters (T5): 3 WGs/CU run desynced phases, so the MFMA-phase wave
// wins issue arbitration against other WGs' staging waves.
__global__ __launch_bounds__(256, 3) void fused_attn(
    const float* __restrict__ voxel, const float* __restrict__ cnnf,
    const float* __restrict__ gamma, const float* __restrict__ beta,
    const unsigned short* __restrict__ W1bp, const unsigned short* __restrict__ W2bp,
    float* __restrict__ out)
{
    // xs  : [64 tok][128 pos] bf16 swizzled (x)          16384 B  (rows 0-31 of yf)
    // obuf: [64 tok][128 pos] bf16 swizzled (O)          16384 B  (rows 32-63 of yf)
    // yf  : [64 tok][128 ch]  f32 swizzled — overlays BOTH after ofr reads (B2.5)
    __shared__ __align__(16) char smem[32768];
    unsigned short* xs   = (unsigned short*)smem;
    unsigned short* obuf = (unsigned short*)(smem + 16384);
    float* yf = (float*)smem;

    const int tid = threadIdx.x;
    const int wave = tid >> 6, lane = tid & 63;
    const int lrow = lane & 15, lk = lane >> 4;
    const int w = wave;                 // n-split: this wave owns heads {w, w+4}
    const int r7 = lrow & 7;
    const int tok0 = blockIdx.x * 64;

    // ---- prefetch first two W1 A-tiles (hide under staging) ----
    bf16x8 A[2][4];
    #pragma unroll
    for (int kk = 0; kk < 4; ++kk) {
        A[0][kk] = *(const bf16x8*)(W1bp + ((size_t)(((0 * 8 + w) * 4 + kk) * 64 + lane)) * 8);
        A[1][kk] = *(const bf16x8*)(W1bp + ((size_t)(((1 * 8 + w) * 4 + kk) * 64 + lane)) * 8);
    }

    // ---- phase 1: stage x -> bf16 swizzled LDS (64 tokens) ----
    for (int i = tid; i < 64 * 30; i += 256) {
        int r = i / 30, c4 = i % 30;
        int gtok = tok0 + r;
        const float* src = ((gtok & 1) ? cnnf : voxel) + (size_t)(gtok >> 1) * DD + c4 * 4;
        float4 f = *(const float4*)src;
        ushort4 hv;
        hv.x = f2bf(f.x); hv.y = f2bf(f.y); hv.z = f2bf(f.z); hv.w = f2bf(f.w);
        int c8 = c4 >> 1, sub = (c4 & 1) * 8;
        *(ushort4*)((char*)xs + r * 256 + ((c8 ^ (r & 7)) << 4) + sub) = hv;
    }
    if (tid < 64) {   // pad chunk 15: x[120]=1.0 (bias channel), 121..127 = 0
        int r = tid;
        ushort4 p0; p0.x = 0x3F80; p0.y = 0; p0.z = 0; p0.w = 0;
        ushort4 z0; z0.x = 0; z0.y = 0; z0.z = 0; z0.w = 0;
        char* base = (char*)xs + r * 256 + ((15 ^ (r & 7)) << 4);
        *(ushort4*)base = p0;
        *(ushort4*)(base + 8) = z0;
    }
    __syncthreads();   // B1

    // ---- B-frags for all 4 token-tiles into registers ----
    bf16x8 bfr[4][4];
    #pragma unroll
    for (int b = 0; b < 4; ++b)
        #pragma unroll
        for (int kk = 0; kk < 4; ++kk) {
            int chunk = kk * 4 + lk;
            bfr[b][kk] = *(const bf16x8*)((const char*)xs + (b * 16 + lrow) * 256 + ((chunk ^ r7) << 4));
        }

    // ---- phase 2+3: QKV GEMM + attention, head-sequential ----
    const float scale = 0.25819888974716112567f;   // 1/sqrt(15)
    #pragma unroll
    for (int hh = 0; hh < 2; ++hh) {
        int h = w + 4 * hh;
        f32x4 acc[3][4];
        __builtin_amdgcn_s_setprio(1);
        #pragma unroll
        for (int part = 0; part < 3; ++part) {
            int u = hh * 3 + part;
            #pragma unroll
            for (int b = 0; b < 4; ++b) {
                f32x4 a = {0.f, 0.f, 0.f, 0.f};
                #pragma unroll
                for (int kk = 0; kk < 4; ++kk)
                    a = __builtin_amdgcn_mfma_f32_16x16x32_bf16(A[u & 1][kk], bfr[b][kk], a, 0, 0, 0);
                acc[part][b] = a;
            }
            if (u + 2 < 6) {   // prefetch tile T[u+2] into the buffer just consumed
                int v = u + 2;
                int t2 = (v % 3) * 8 + (w + 4 * (v / 3));
                #pragma unroll
                for (int kk = 0; kk < 4; ++kk)
                    A[u & 1][kk] = *(const bf16x8*)(W1bp + ((size_t)((t2 * 4 + kk) * 64 + lane)) * 8);
            }
        }
        __builtin_amdgcn_s_setprio(0);
        #pragma unroll
        for (int b = 0; b < 4; ++b) {
            f32x4 Q = acc[0][b], K = acc[1][b], V = acc[2][b];
            float kn0 = __shfl_xor(K[0], 1), kn1 = __shfl_xor(K[1], 1);
            float kn2 = __shfl_xor(K[2], 1), kn3 = __shfl_xor(K[3], 1);
            float ps = Q[0] * K[0] + Q[1] * K[1] + Q[2] * K[2] + Q[3] * K[3];
            float pn = Q[0] * kn0 + Q[1] * kn1 + Q[2] * kn2 + Q[3] * kn3;
            ps += __shfl_xor(ps, 16); ps += __shfl_xor(ps, 32);
            pn += __shfl_xor(pn, 16); pn += __shfl_xor(pn, 32);
            // softmax over 2 logits == sigmoid of the difference (safe at +/-inf)
            float d = (pn - ps) * scale;
            float p0 = 1.f / (1.f + __expf(d));
            float p1 = 1.f - p0;
            float o0 = p0 * V[0] + p1 * __shfl_xor(V[0], 1);
            float o1 = p0 * V[1] + p1 * __shfl_xor(V[1], 1);
            float o2 = p0 * V[2] + p1 * __shfl_xor(V[2], 1);
            float o3 = p0 * V[3] + p1 * __shfl_xor(V[3], 1);
            unsigned w0 = (unsigned)f2bf(o0) | ((unsigned)f2bf(o1) << 16);
            unsigned w1v = (unsigned)f2bf(o2) | ((unsigned)f2bf(o3) << 16);
            int chunk = 2 * h + (lk >> 1);
            *(uint2*)((char*)obuf + (b * 16 + lrow) * 256 + ((chunk ^ r7) << 4) + (lk & 1) * 8)
                = make_uint2(w0, w1v);
        }
    }

    // prefetch this wave's two W2 A-tiles (t = w, w+4) before the barrier
    bf16x8 A2[2][4];
    #pragma unroll
    for (int ti = 0; ti < 2; ++ti)
        #pragma unroll
        for (int kk = 0; kk < 4; ++kk)
            A2[ti][kk] = *(const bf16x8*)(W2bp + ((size_t)(((w + 4 * ti) * 4 + kk) * 64 + lane)) * 8);
    __syncthreads();   // B2

    // ---- phase 4: out projection, 4-way n-split over 8 W2 tiles; y stays f32 ----
    {
        bf16x8 ofr[4][4];
        #pragma unroll
        for (int b = 0; b < 4; ++b)
            #pragma unroll
            for (int kk = 0; kk < 4; ++kk) {
                int chunk = kk * 4 + lk;
                ofr[b][kk] = *(const bf16x8*)((const char*)obuf + (b * 16 + lrow) * 256 + ((chunk ^ r7) << 4));
            }
        __syncthreads();   // B2.5: all ofr reads done -> xs+obuf regions reusable as yf
        __builtin_amdgcn_s_setprio(1);
        #pragma unroll
        for (int ti = 0; ti < 2; ++ti) {
            int t = w + 4 * ti;
            int chunk = 4 * t + lk;            // 16B f32 chunk = channels 16t+4lk..+3
            #pragma unroll
            for (int b = 0; b < 4; ++b) {
                f32x4 a = {0.f, 0.f, 0.f, 0.f};
                #pragma unroll
                for (int kk = 0; kk < 4; ++kk)
                    a = __builtin_amdgcn_mfma_f32_16x16x32_bf16(A2[ti][kk], ofr[b][kk], a, 0, 0, 0);
                int row = b * 16 + lrow;
                *(f32x4*)((char*)yf + row * 512 + ((chunk ^ r7) << 4)) = a;
            }
        }
        __builtin_amdgcn_s_setprio(0);
    }
    __syncthreads();   // B3

    // ---- phase 5: LayerNorm + mean-pool, 8 threads per location (f32 y) ----
    {
        int locl = tid >> 3;          // 0..31
        int s = tid & 7;              // chunk group
        int r0 = 2 * locl, r1 = r0 + 1;
        auto rdf = [&](int r, int c) -> f32x4 {
            return *(const f32x4*)((const char*)yf + r * 512 + ((c ^ (r & 7)) << 4));
        };
        // thread covers channels [8s..8s+7] and [64+8s..64+8s+7] of both rows
        f32x4 v00 = rdf(r0, 2 * s),      v01 = rdf(r0, 2 * s + 1);
        f32x4 v02 = rdf(r0, 16 + 2 * s), v03 = rdf(r0, 16 + 2 * s + 1);
        f32x4 v10 = rdf(r1, 2 * s),      v11 = rdf(r1, 2 * s + 1);
        f32x4 v12 = rdf(r1, 16 + 2 * s), v13 = rdf(r1, 16 + 2 * s + 1);
        float a0[16], a1[16];
        #pragma unroll
        for (int j = 0; j < 4; ++j) {
            a0[j] = v00[j]; a0[4 + j] = v01[j]; a0[8 + j] = v02[j]; a0[12 + j] = v03[j];
            a1[j] = v10[j]; a1[4 + j] = v11[j]; a1[8 + j] = v12[j]; a1[12 + j] = v13[j];
        }
        float sum0 = 0.f, sq0 = 0.f, sum1 = 0.f, sq1 = 0.f;
        #pragma unroll
        for (int j = 0; j < 16; ++j) {   // pad channels (>=120) are exact zeros
            sum0 += a0[j]; sq0 += a0[j] * a0[j];
            sum1 += a1[j]; sq1 += a1[j] * a1[j];
        }
        #pragma unroll
        for (int ww = 1; ww < 8; ww <<= 1) {
            sum0 += __shfl_xor(sum0, ww); sq0 += __shfl_xor(sq0, ww);
            sum1 += __shfl_xor(sum1, ww); sq1 += __shfl_xor(sq1, ww);
        }
        const float inv = 1.f / 120.f;
        float mu0 = sum0 * inv, mu1 = sum1 * inv;
        float var0 = sq0 * inv - mu0 * mu0, var1 = sq1 * inv - mu1 * mu1;
        float rs0 = rsqrtf(var0 + LN_EPS), rs1 = rsqrtf(var1 + LN_EPS);
        float* op = out + (size_t)(blockIdx.x * 32 + locl) * DD;
        // first 8 channels: c = 8*s (always < 120)
        {
            int c = 8 * s;
            #pragma unroll
            for (int q = 0; q < 2; ++q) {
                f32x4 gm = *(const f32x4*)(gamma + c + 4 * q);
                f32x4 bt = *(const f32x4*)(beta + c + 4 * q);
                float4 o4;
                float z0, z1;
                z0 = (a0[4 * q + 0] - mu0) * rs0; z1 = (a1[4 * q + 0] - mu1) * rs1;
                o4.x = 0.5f * (z0 + z1) * gm[0] + bt[0];
                z0 = (a0[4 * q + 1] - mu0) * rs0; z1 = (a1[4 * q + 1] - mu1) * rs1;
                o4.y = 0.5f * (z0 + z1) * gm[1] + bt[1];
                z0 = (a0[4 * q + 2] - mu0) * rs0; z1 = (a1[4 * q + 2] - mu1) * rs1;
                o4.z = 0.5f * (z0 + z1) * gm[2] + bt[2];
                z0 = (a0[4 * q + 3] - mu0) * rs0; z1 = (a1[4 * q + 3] - mu1) * rs1;
                o4.w = 0.5f * (z0 + z1) * gm[3] + bt[3];
                *(float4*)(op + c + 4 * q) = o4;
            }
        }
        // second 8 channels: c = 64 + 8*s (skip s==7: channels 120..127 are pad)
        if (s < 7) {
            int c = 64 + 8 * s;
            #pragma unroll
            for (int q = 0; q < 2; ++q) {
                f32x4 gm = *(const f32x4*)(gamma + c + 4 * q);
                f32x4 bt = *(const f32x4*)(beta + c + 4 * q);
                float4 o4;
                float z0, z1;
                z0 = (a0[8 + 4 * q + 0] - mu0) * rs0; z1 = (a1[8 + 4 * q + 0] - mu1) * rs1;
                o4.x = 0.5f * (z0 + z1) * gm[0] + bt[0];
                z0 = (a0[8 + 4 * q + 1] - mu0) * rs0; z1 = (a1[8 + 4 * q + 1] - mu1) * rs1;
                o4.y = 0.5f * (z0 + z1) * gm[1] + bt[1];
                z0 = (a0[8 + 4 * q + 2] - mu0) * rs0; z1 = (a1[8 + 4 * q + 2] - mu1) * rs1;
                o4.z = 0.5f * (z0 + z1) * gm[2] + bt[2];
                z0 = (a0[8 + 4 * q + 3] - mu0) * rs0; z1 = (a1[8 + 4 * q + 3] - mu1) * rs1;
                o4.w = 0.5f * (z0 + z1) * gm[3] + bt[3];
                *(float4*)(op + c + 4 * q) = o4;
            }
        }
    }
}

extern "C" void kernel_launch(void* const* d_in, const int* in_sizes, int n_in,
                              void* d_out, int out_size, void* d_ws, size_t ws_size,
                              hipStream_t stream) {
    const float* voxel = (const float*)d_in[0];
    const float* cnnf  = (const float*)d_in[1];
    const float* w1    = (const float*)d_in[2];
    const float* b1    = (const float*)d_in[3];
    const float* w2    = (const float*)d_in[4];
    const float* b2    = (const float*)d_in[5];
    const float* gamma = (const float*)d_in[6];
    const float* beta  = (const float*)d_in[7];
    float* out = (float*)d_out;

    unsigned short* W1bp = (unsigned short*)d_ws;                    // 24*4*64*8*2 = 98304 B
    unsigned short* W2bp = (unsigned short*)((char*)d_ws + 98304);   // 8*4*64*8*2  = 32768 B

    int nloc = in_sizes[0] / DD;   // 131072 locations
    prep_weights<<<128, 256, 0, stream>>>(w1, w2, b1, b2, W1bp, W2bp);
    fused_attn<<<nloc / 32, 256, 0, stream>>>(voxel, cnnf, gamma, beta, W1bp, W2bp, out);
}